// Round 11
// baseline (2081.272 us; speedup 1.0000x reference)
//
#include <hip/hip_runtime.h>

#define T_STEPS 250
#define BATCH   256
#define IN_DIM  700
#define HID     1024
#define W_LD    1724   // = IN_DIM + HID
#define OUT_DIM 20
#define KP      704    // K padded to 22*32
#define KP4     (KP / 4)
#define NKT     (KP / 32)
#define CHUNK_T 50     // CUR chunk: 52 MB -> cache-resident (r8: FETCH 137->35MB)

typedef __attribute__((ext_vector_type(8))) short     bf16x8;
typedef __attribute__((ext_vector_type(8))) unsigned short u16x8;
typedef __attribute__((ext_vector_type(4))) float     f32x4;
typedef unsigned long long u64;

__device__ inline unsigned short f2bf(float f) {
    unsigned int u = __float_as_uint(f);
    unsigned int r = u + 0x7FFFu + ((u >> 16) & 1u);
    return (unsigned short)(r >> 16);
}

// ---------------------------------------------------------------------------
// WhhT_bf16[j][h] = bf16(W_h[h][700 + j]);  row 1024 is a zero sentinel row.
// ---------------------------------------------------------------------------
__global__ __launch_bounds__(256)
void trans_whh_bf16(const float* __restrict__ W_h, unsigned short* __restrict__ WhhT) {
    __shared__ float tile[32][33];
    const int bx = blockIdx.x * 32;  // h base
    const int by = blockIdx.y * 32;  // j base
    const int tx = threadIdx.x, ty = threadIdx.y;
#pragma unroll
    for (int i = 0; i < 32; i += 8)
        tile[ty + i][tx] = W_h[(size_t)(bx + ty + i) * W_LD + IN_DIM + by + tx];
    __syncthreads();
#pragma unroll
    for (int i = 0; i < 32; i += 8)
        WhhT[(size_t)(by + ty + i) * HID + bx + tx] = f2bf(tile[tx][ty + i]);
}

// WoT[h][o] = Wo[o][h]
__global__ __launch_bounds__(256)
void trans_wo(const float* __restrict__ Wo, float* __restrict__ WoT) {
    const int h = blockIdx.x * 256 + threadIdx.x;
    if (h >= HID) return;
#pragma unroll
    for (int o = 0; o < OUT_DIM; ++o)
        WoT[(size_t)h * OUT_DIM + o] = Wo[(size_t)o * HID + h];
}

// ---------------------------------------------------------------------------
// Pack x rows -> zero-padded K=704 bf16
// ---------------------------------------------------------------------------
__global__ __launch_bounds__(256)
void pack_x_bf16(const float* __restrict__ x, unsigned short* __restrict__ Xp, int rows) {
    const int total = rows * KP4;
    for (int idx = blockIdx.x * blockDim.x + threadIdx.x; idx < total;
         idx += gridDim.x * blockDim.x) {
        const int r = idx / KP4;
        const int c = idx - r * KP4;
        ushort4 o = make_ushort4(0, 0, 0, 0);
        if (c < IN_DIM / 4) {
            float4 v = *(const float4*)(x + (size_t)r * IN_DIM + c * 4);
            o = make_ushort4(f2bf(v.x), f2bf(v.y), f2bf(v.z), f2bf(v.w));
        }
        ((ushort4*)Xp)[(size_t)r * KP4 + c] = o;
    }
}

// Pack W_h's first 700 cols (ld 1724) -> [1024][704] bf16
__global__ __launch_bounds__(256)
void pack_w_bf16(const float* __restrict__ W_h, unsigned short* __restrict__ Wp) {
    const int total = HID * KP4;
    for (int idx = blockIdx.x * blockDim.x + threadIdx.x; idx < total;
         idx += gridDim.x * blockDim.x) {
        const int r = idx / KP4;
        const int c = idx - r * KP4;
        ushort4 o = make_ushort4(0, 0, 0, 0);
        if (c < IN_DIM / 4) {
            float4 v = *(const float4*)(W_h + (size_t)r * W_LD + c * 4);
            o = make_ushort4(f2bf(v.x), f2bf(v.y), f2bf(v.z), f2bf(v.w));
        }
        ((ushort4*)Wp)[(size_t)r * KP4 + c] = o;
    }
}

// ---------------------------------------------------------------------------
// bf16 MFMA GEMM: 128x128 tile, BK=32, 4 waves. (unchanged)
// ---------------------------------------------------------------------------
__global__ __launch_bounds__(256)
void mfma_gemm(const unsigned short* __restrict__ A,
               const unsigned short* __restrict__ B, float* __restrict__ C) {
    __shared__ unsigned short lA[128 * 32];
    __shared__ unsigned short lB[128 * 32];
    const int tid  = threadIdx.x;
    const int wid  = tid >> 6, lane = tid & 63;
    const int wr   = wid >> 1, wc = wid & 1;
    const size_t bm = (size_t)blockIdx.x * 128;
    const size_t bn = (size_t)blockIdx.y * 128;

    const int srow = tid >> 2;
    const int skq  = (tid & 3) * 8;

    const int wb0 = (srow * 64 + (tid & 3) * 16) ^ ((srow & 7) << 4);
    const int wb1 = ((srow + 64) * 64 + (tid & 3) * 16) ^ ((srow & 7) << 4);

    const unsigned short* pa = A + (bm + srow) * KP + skq;
    const unsigned short* pb = B + (bn + srow) * KP + skq;

    u16x8 ra0, ra1, rb0, rb1;
    auto ldg = [&](int k0) {
        ra0 = *(const u16x8*)(pa + k0);
        ra1 = *(const u16x8*)(pa + (size_t)64 * KP + k0);
        rb0 = *(const u16x8*)(pb + k0);
        rb1 = *(const u16x8*)(pb + (size_t)64 * KP + k0);
    };

    const int arow = wr * 64 + (lane & 15);
    const int brow = wc * 64 + (lane & 15);
    const int fq   = (lane >> 4) * 16;

    f32x4 acc[4][4];
#pragma unroll
    for (int m = 0; m < 4; ++m)
#pragma unroll
        for (int n = 0; n < 4; ++n) acc[m][n] = (f32x4){0.f, 0.f, 0.f, 0.f};

    ldg(0);
    for (int kt = 0; kt < NKT; ++kt) {
        *(u16x8*)((char*)lA + wb0) = ra0;
        *(u16x8*)((char*)lA + wb1) = ra1;
        *(u16x8*)((char*)lB + wb0) = rb0;
        *(u16x8*)((char*)lB + wb1) = rb1;
        __syncthreads();
        if (kt + 1 < NKT) ldg((kt + 1) * 32);
        bf16x8 af[4], bf[4];
#pragma unroll
        for (int m = 0; m < 4; ++m) {
            const int row = arow + m * 16;
            af[m] = *(const bf16x8*)((const char*)lA + ((row * 64 + fq) ^ ((row & 7) << 4)));
        }
#pragma unroll
        for (int n = 0; n < 4; ++n) {
            const int row = brow + n * 16;
            bf[n] = *(const bf16x8*)((const char*)lB + ((row * 64 + fq) ^ ((row & 7) << 4)));
        }
#pragma unroll
        for (int m = 0; m < 4; ++m)
#pragma unroll
            for (int n = 0; n < 4; ++n)
                acc[m][n] = __builtin_amdgcn_mfma_f32_16x16x32_bf16(af[m], bf[n], acc[m][n], 0, 0, 0);
        __syncthreads();
    }
#pragma unroll
    for (int m = 0; m < 4; ++m)
#pragma unroll
        for (int r = 0; r < 4; ++r) {
            float* cp = C + (bm + wr * 64 + m * 16 + (lane >> 4) * 4 + r) * HID
                          + bn + wc * 64 + (lane & 15);
#pragma unroll
            for (int n = 0; n < 4; ++n) cp[n * 16] = acc[m][n][r];
        }
}

// ---------------------------------------------------------------------------
// Persistent ALIF scan v8: 1 block = 1 wave = 1 batch, 16 neurons/lane.
// NO LDS, NO barriers, NO shfl-prefix, NO scatter: spike set carried as 16
// scalar ballot masks; index extraction = scalar s_ff1 chain; gather address
// = SGPR base + fixed lane offset. 2-deep parity-register load pipeline.
// Sum order is k-major (bit k, then lane) — deterministic.
// ---------------------------------------------------------------------------
#define ACCP(c0_, c1_) {                                                      \
    rec[0]  += __uint_as_float(c0_.x << 16);                                  \
    rec[1]  += __uint_as_float(c0_.x & 0xFFFF0000u);                          \
    rec[2]  += __uint_as_float(c0_.y << 16);                                  \
    rec[3]  += __uint_as_float(c0_.y & 0xFFFF0000u);                          \
    rec[4]  += __uint_as_float(c0_.z << 16);                                  \
    rec[5]  += __uint_as_float(c0_.z & 0xFFFF0000u);                          \
    rec[6]  += __uint_as_float(c0_.w << 16);                                  \
    rec[7]  += __uint_as_float(c0_.w & 0xFFFF0000u);                          \
    rec[8]  += __uint_as_float(c1_.x << 16);                                  \
    rec[9]  += __uint_as_float(c1_.x & 0xFFFF0000u);                          \
    rec[10] += __uint_as_float(c1_.y << 16);                                  \
    rec[11] += __uint_as_float(c1_.y & 0xFFFF0000u);                          \
    rec[12] += __uint_as_float(c1_.z << 16);                                  \
    rec[13] += __uint_as_float(c1_.z & 0xFFFF0000u);                          \
    rec[14] += __uint_as_float(c1_.w << 16);                                  \
    rec[15] += __uint_as_float(c1_.w & 0xFFFF0000u); }

__global__ __launch_bounds__(64, 1)
void alif_scan(const float* __restrict__ CUR, const unsigned short* __restrict__ WhhT,
               const float* __restrict__ tau_mem, const float* __restrict__ tau_adp,
               float* __restrict__ zS, float* __restrict__ uS, float* __restrict__ aS,
               float* __restrict__ spkS, unsigned short* __restrict__ masks16,
               int t0, int tc) {
    const int b    = blockIdx.x;
    const int lane = threadIdx.x;      // 0..63
    const int h0   = lane * 16;

    float u[16], a[16], alpha[16], rho[16];
#pragma unroll
    for (int q = 0; q < 4; ++q) {
        f32x4 uu = *(const f32x4*)(uS + (size_t)b * HID + h0 + q * 4);
        f32x4 aa = *(const f32x4*)(aS + (size_t)b * HID + h0 + q * 4);
        f32x4 tm = *(const f32x4*)(tau_mem + h0 + q * 4);
        f32x4 ta = *(const f32x4*)(tau_adp + h0 + q * 4);
#pragma unroll
        for (int k = 0; k < 4; ++k) {
            u[q * 4 + k] = uu[k];  a[q * 4 + k] = aa[k];
            alpha[q * 4 + k] = expf(-1.f / tm[k]);
            rho[q * 4 + k]   = expf(-1.f / ta[k]);
        }
    }
    unsigned int zb = 0;
#pragma unroll
    for (int q = 0; q < 4; ++q) {
        f32x4 zz = *(const f32x4*)(zS + (size_t)b * HID + h0 + q * 4);
#pragma unroll
        for (int k = 0; k < 4; ++k)
            if (zz[k] > 0.5f) zb |= (1u << (q * 4 + k));
    }

    const unsigned int* Wrow32 = (const unsigned int*)WhhT + (h0 >> 1);
    float xc[16];
#pragma unroll
    for (int q = 0; q < 4; ++q) {
        f32x4 v = *(const f32x4*)(CUR + (size_t)b * HID + h0 + q * 4);
        xc[q*4+0]=v[0]; xc[q*4+1]=v[1]; xc[q*4+2]=v[2]; xc[q*4+3]=v[3];
    }

    int wspk = 0;
    for (int tt = 0; tt < tc; ++tt) {
        // prefetch next step's input current (cache-resident chunk)
        float xn[16];
        {
            const int tn = (tt + 1 < tc) ? tt + 1 : tt;
            const float* p = CUR + ((size_t)tn * BATCH + b) * HID + h0;
#pragma unroll
            for (int q = 0; q < 4; ++q) {
                f32x4 v = *(const f32x4*)(p + q * 4);
                xn[q*4+0]=v[0]; xn[q*4+1]=v[1]; xn[q*4+2]=v[2]; xn[q*4+3]=v[3];
            }
        }

        float rec[16];
#pragma unroll
        for (int k = 0; k < 16; ++k) rec[k] = 0.f;

        // ---- gather via scalar ballot masks; 2-deep parity pipeline ----
        uint4 ra0 = {0,0,0,0}, ra1 = {0,0,0,0};
        uint4 rb0 = {0,0,0,0}, rb1 = {0,0,0,0};
        int np = 0;    // uniform spike counter
#pragma unroll
        for (int k = 0; k < 16; ++k) {
            unsigned long long m = __ballot(((zb >> k) & 1u) != 0u);
            while (m) {
                const int l = (int)__ffsll(m) - 1;
                m &= m - 1;
                const unsigned int* p = Wrow32 + ((size_t)(l * 16 + k) << 9);
                if (np & 1) {
                    if (np >= 2) ACCP(rb0, rb1);
                    rb0 = *(const uint4*)p;
                    rb1 = *(const uint4*)(p + 4);
                } else {
                    if (np >= 2) ACCP(ra0, ra1);
                    ra0 = *(const uint4*)p;
                    ra1 = *(const uint4*)(p + 4);
                }
                ++np;
            }
        }
        if (np >= 2) {          // flush oldest-first
            if (np & 1) { ACCP(rb0, rb1); ACCP(ra0, ra1); }
            else        { ACCP(ra0, ra1); ACCP(rb0, rb1); }
        } else if (np == 1) {
            ACCP(ra0, ra1);
        }

        // ---- neuron update ----
        unsigned int znb = 0;
#pragma unroll
        for (int k = 0; k < 16; ++k) {
            const float z   = (zb >> k) & 1 ? 1.f : 0.f;
            const float omr = 1.f - rho[k];
            const float oma = 1.f - alpha[k];
            a[k] = rho[k] * a[k] + omr * z;
            const float th = 0.01f + 1.8f * a[k];
            u[k] = alpha[k] * u[k] + oma * (xc[k] + rec[k]) - z * th;
            if (u[k] - th > 0.f) znb |= (1u << k);
        }
        zb = znb;
        wspk += __popc(zb);
        masks16[((size_t)(t0 + tt) * BATCH + b) * 64 + lane] = (unsigned short)zb;

#pragma unroll
        for (int k = 0; k < 16; ++k) xc[k] = xn[k];
    }

    // write back state
#pragma unroll
    for (int k = 0; k < 16; ++k) {
        zS[(size_t)b * HID + h0 + k] = (zb >> k) & 1 ? 1.f : 0.f;
        uS[(size_t)b * HID + h0 + k] = u[k];
        aS[(size_t)b * HID + h0 + k] = a[k];
    }
#pragma unroll
    for (int d = 32; d > 0; d >>= 1) wspk += __shfl_down(wspk, d, 64);
    if (lane == 0) atomicAdd(spkS, (float)wspk);
}

// ---------------------------------------------------------------------------
// y[t*B+b][o] = sum over spiking j of WoT[j][o]  (one wave per (t,b) pair)
// ---------------------------------------------------------------------------
__global__ __launch_bounds__(256)
void readout_y(const u64* __restrict__ masks, const float* __restrict__ WoT,
               float* __restrict__ y, int npairs) {
    const int pr   = blockIdx.x * 4 + (threadIdx.x >> 6);
    const int lane = threadIdx.x & 63;
    if (pr >= npairs) return;
    const u64* mp = masks + (size_t)pr * 16;
    float acc = 0.f;
#pragma unroll 4
    for (int w = 0; w < 16; ++w) {
        u64 m = mp[w];
        while (m) {
            const int j = __ffsll((unsigned long long)m) - 1;
            m &= m - 1;
            if (lane < OUT_DIM) acc += WoT[(size_t)(w * 64 + j) * OUT_DIM + lane];
        }
    }
    if (lane < OUT_DIM) y[(size_t)pr * OUT_DIM + lane] = acc;
}

// ---------------------------------------------------------------------------
// outputs[t][b][o] = EWA over t of y; writes final ouT.
// ---------------------------------------------------------------------------
__global__ __launch_bounds__(256)
void ewa_out(const float* __restrict__ y, const float* __restrict__ tau_out,
             float* __restrict__ outputs, float* __restrict__ ouS) {
    const int idx = blockIdx.x * 256 + threadIdx.x;
    if (idx >= BATCH * OUT_DIM) return;
    const int o = idx % OUT_DIM;
    const float ao = expf(-1.f / tau_out[o]);
    float ou = ouS[idx];
    for (int t = 0; t < T_STEPS; ++t) {
        const float v = y[(size_t)t * BATCH * OUT_DIM + idx];
        ou = ao * ou + (1.f - ao) * v;
        outputs[(size_t)t * BATCH * OUT_DIM + idx] = ou;
    }
    ouS[idx] = ou;
}

// ---------------------------------------------------------------------------
extern "C" void kernel_launch(void* const* d_in, const int* in_sizes, int n_in,
                              void* d_out, int out_size, void* d_ws, size_t ws_size,
                              hipStream_t stream) {
    (void)in_sizes; (void)n_in; (void)out_size;
    const float* x       = (const float*)d_in[0];
    const float* W_h     = (const float*)d_in[1];
    const float* tau_mem = (const float*)d_in[2];
    const float* tau_adp = (const float*)d_in[3];
    const float* W_o     = (const float*)d_in[4];
    const float* tau_out = (const float*)d_in[5];

    float* out     = (float*)d_out;
    float* outputs = out;                                      // [250][256][20]
    float* zS  = out + (size_t)T_STEPS * BATCH * OUT_DIM;      // [256][1024]
    float* uS  = zS + (size_t)BATCH * HID;
    float* aS  = uS + (size_t)BATCH * HID;
    float* ouS = aS + (size_t)BATCH * HID;                     // [256][20]
    float* spk = ouS + (size_t)BATCH * OUT_DIM;                // scalar

    // ws layout (bytes)
    char* w = (char*)d_ws;
    unsigned short* WhhT = (unsigned short*)w; w += (size_t)(HID + 1) * HID * 2;  // 2 MB + zero row
    unsigned short* Wp   = (unsigned short*)w; w += (size_t)HID * KP * 2;         // 1.4 MB
    float*          WoT  = (float*)w;          w += (size_t)HID * OUT_DIM * 4;    // 80 KB
    unsigned short* masks16 = (unsigned short*)w; w += (size_t)T_STEPS * BATCH * 128; // 8 MB
    float*          yBuf = (float*)w;          w += (size_t)T_STEPS * BATCH * OUT_DIM * 4; // 5 MB
    char*           dynb = w;

    const size_t fixed = (size_t)(dynb - (char*)d_ws);
    const size_t per_step = (size_t)BATCH * KP * 2 + (size_t)BATCH * HID * 4;
    const size_t avail = ws_size > fixed ? ws_size - fixed : 0;
    int CT = (int)(avail / per_step);
    if (CT > CHUNK_T) CT = CHUNK_T;
    if (CT < 1) CT = 1;

    hipMemsetAsync(zS, 0,
                   ((size_t)3 * BATCH * HID + BATCH * OUT_DIM + 1) * sizeof(float),
                   stream);
    hipMemsetAsync(WhhT + (size_t)HID * HID, 0, HID * sizeof(unsigned short), stream);
    trans_whh_bf16<<<dim3(32, 32), dim3(32, 8), 0, stream>>>(W_h, WhhT);
    pack_w_bf16<<<512, 256, 0, stream>>>(W_h, Wp);
    trans_wo<<<4, 256, 0, stream>>>(W_o, WoT);

    for (int t0 = 0; t0 < T_STEPS; t0 += CT) {
        const int tc = (T_STEPS - t0 < CT) ? (T_STEPS - t0) : CT;
        const int rows = tc * BATCH;
        unsigned short* Xp = (unsigned short*)dynb;
        float* CUR = (float*)(dynb + (size_t)rows * KP * 2);
        int pblocks = (rows * KP4 + 255) / 256;
        if (pblocks > 2048) pblocks = 2048;
        pack_x_bf16<<<pblocks, 256, 0, stream>>>(x + (size_t)t0 * BATCH * IN_DIM, Xp, rows);
        mfma_gemm<<<dim3(rows / 128, HID / 128), 256, 0, stream>>>(Xp, Wp, CUR);
        alif_scan<<<BATCH, 64, 0, stream>>>(CUR, WhhT, tau_mem, tau_adp,
                                            zS, uS, aS, spk, masks16, t0, tc);
    }

    const int npairs = T_STEPS * BATCH;
    readout_y<<<(npairs + 3) / 4, 256, 0, stream>>>((const u64*)masks16, WoT, yBuf, npairs);
    ewa_out<<<(BATCH * OUT_DIM + 255) / 256, 256, 0, stream>>>(yBuf, tau_out, outputs, ouS);
}

// Round 12
// 1077.369 us; speedup vs baseline: 1.9318x; 1.9318x over previous
//
#include <hip/hip_runtime.h>

#define T_STEPS 250
#define BATCH   256
#define IN_DIM  700
#define HID     1024
#define W_LD    1724   // = IN_DIM + HID
#define OUT_DIM 20
#define KP      704    // K padded to 22*32
#define KP4     (KP / 4)
#define NKT     (KP / 32)
#define CHUNK_T 50     // CUR chunk: 52 MB -> cache-resident (r8: FETCH 137->35MB)

typedef __attribute__((ext_vector_type(8))) short     bf16x8;
typedef __attribute__((ext_vector_type(8))) unsigned short u16x8;
typedef __attribute__((ext_vector_type(4))) float     f32x4;
typedef unsigned long long u64;

__device__ inline unsigned short f2bf(float f) {
    unsigned int u = __float_as_uint(f);
    unsigned int r = u + 0x7FFFu + ((u >> 16) & 1u);
    return (unsigned short)(r >> 16);
}

// ---------------------------------------------------------------------------
// WhhT_bf16[j][h] = bf16(W_h[h][700 + j]);  row 1024 is a zero sentinel row.
// ---------------------------------------------------------------------------
__global__ __launch_bounds__(256)
void trans_whh_bf16(const float* __restrict__ W_h, unsigned short* __restrict__ WhhT) {
    __shared__ float tile[32][33];
    const int bx = blockIdx.x * 32;  // h base
    const int by = blockIdx.y * 32;  // j base
    const int tx = threadIdx.x, ty = threadIdx.y;
#pragma unroll
    for (int i = 0; i < 32; i += 8)
        tile[ty + i][tx] = W_h[(size_t)(bx + ty + i) * W_LD + IN_DIM + by + tx];
    __syncthreads();
#pragma unroll
    for (int i = 0; i < 32; i += 8)
        WhhT[(size_t)(by + ty + i) * HID + bx + tx] = f2bf(tile[tx][ty + i]);
}

// WoT[h][o] = Wo[o][h]
__global__ __launch_bounds__(256)
void trans_wo(const float* __restrict__ Wo, float* __restrict__ WoT) {
    const int h = blockIdx.x * 256 + threadIdx.x;
    if (h >= HID) return;
#pragma unroll
    for (int o = 0; o < OUT_DIM; ++o)
        WoT[(size_t)h * OUT_DIM + o] = Wo[(size_t)o * HID + h];
}

// ---------------------------------------------------------------------------
// Pack x rows -> zero-padded K=704 bf16
// ---------------------------------------------------------------------------
__global__ __launch_bounds__(256)
void pack_x_bf16(const float* __restrict__ x, unsigned short* __restrict__ Xp, int rows) {
    const int total = rows * KP4;
    for (int idx = blockIdx.x * blockDim.x + threadIdx.x; idx < total;
         idx += gridDim.x * blockDim.x) {
        const int r = idx / KP4;
        const int c = idx - r * KP4;
        ushort4 o = make_ushort4(0, 0, 0, 0);
        if (c < IN_DIM / 4) {
            float4 v = *(const float4*)(x + (size_t)r * IN_DIM + c * 4);
            o = make_ushort4(f2bf(v.x), f2bf(v.y), f2bf(v.z), f2bf(v.w));
        }
        ((ushort4*)Xp)[(size_t)r * KP4 + c] = o;
    }
}

// Pack W_h's first 700 cols (ld 1724) -> [1024][704] bf16
__global__ __launch_bounds__(256)
void pack_w_bf16(const float* __restrict__ W_h, unsigned short* __restrict__ Wp) {
    const int total = HID * KP4;
    for (int idx = blockIdx.x * blockDim.x + threadIdx.x; idx < total;
         idx += gridDim.x * blockDim.x) {
        const int r = idx / KP4;
        const int c = idx - r * KP4;
        ushort4 o = make_ushort4(0, 0, 0, 0);
        if (c < IN_DIM / 4) {
            float4 v = *(const float4*)(W_h + (size_t)r * W_LD + c * 4);
            o = make_ushort4(f2bf(v.x), f2bf(v.y), f2bf(v.z), f2bf(v.w));
        }
        ((ushort4*)Wp)[(size_t)r * KP4 + c] = o;
    }
}

// ---------------------------------------------------------------------------
// bf16 MFMA GEMM: 128x128 tile, BK=32, 4 waves. (unchanged)
// ---------------------------------------------------------------------------
__global__ __launch_bounds__(256)
void mfma_gemm(const unsigned short* __restrict__ A,
               const unsigned short* __restrict__ B, float* __restrict__ C) {
    __shared__ unsigned short lA[128 * 32];
    __shared__ unsigned short lB[128 * 32];
    const int tid  = threadIdx.x;
    const int wid  = tid >> 6, lane = tid & 63;
    const int wr   = wid >> 1, wc = wid & 1;
    const size_t bm = (size_t)blockIdx.x * 128;
    const size_t bn = (size_t)blockIdx.y * 128;

    const int srow = tid >> 2;
    const int skq  = (tid & 3) * 8;

    const int wb0 = (srow * 64 + (tid & 3) * 16) ^ ((srow & 7) << 4);
    const int wb1 = ((srow + 64) * 64 + (tid & 3) * 16) ^ ((srow & 7) << 4);

    const unsigned short* pa = A + (bm + srow) * KP + skq;
    const unsigned short* pb = B + (bn + srow) * KP + skq;

    u16x8 ra0, ra1, rb0, rb1;
    auto ldg = [&](int k0) {
        ra0 = *(const u16x8*)(pa + k0);
        ra1 = *(const u16x8*)(pa + (size_t)64 * KP + k0);
        rb0 = *(const u16x8*)(pb + k0);
        rb1 = *(const u16x8*)(pb + (size_t)64 * KP + k0);
    };

    const int arow = wr * 64 + (lane & 15);
    const int brow = wc * 64 + (lane & 15);
    const int fq   = (lane >> 4) * 16;

    f32x4 acc[4][4];
#pragma unroll
    for (int m = 0; m < 4; ++m)
#pragma unroll
        for (int n = 0; n < 4; ++n) acc[m][n] = (f32x4){0.f, 0.f, 0.f, 0.f};

    ldg(0);
    for (int kt = 0; kt < NKT; ++kt) {
        *(u16x8*)((char*)lA + wb0) = ra0;
        *(u16x8*)((char*)lA + wb1) = ra1;
        *(u16x8*)((char*)lB + wb0) = rb0;
        *(u16x8*)((char*)lB + wb1) = rb1;
        __syncthreads();
        if (kt + 1 < NKT) ldg((kt + 1) * 32);
        bf16x8 af[4], bf[4];
#pragma unroll
        for (int m = 0; m < 4; ++m) {
            const int row = arow + m * 16;
            af[m] = *(const bf16x8*)((const char*)lA + ((row * 64 + fq) ^ ((row & 7) << 4)));
        }
#pragma unroll
        for (int n = 0; n < 4; ++n) {
            const int row = brow + n * 16;
            bf[n] = *(const bf16x8*)((const char*)lB + ((row * 64 + fq) ^ ((row & 7) << 4)));
        }
#pragma unroll
        for (int m = 0; m < 4; ++m)
#pragma unroll
            for (int n = 0; n < 4; ++n)
                acc[m][n] = __builtin_amdgcn_mfma_f32_16x16x32_bf16(af[m], bf[n], acc[m][n], 0, 0, 0);
        __syncthreads();
    }
#pragma unroll
    for (int m = 0; m < 4; ++m)
#pragma unroll
        for (int r = 0; r < 4; ++r) {
            float* cp = C + (bm + wr * 64 + m * 16 + (lane >> 4) * 4 + r) * HID
                          + bn + wc * 64 + (lane & 15);
#pragma unroll
            for (int n = 0; n < 4; ++n) cp[n * 16] = acc[m][n][r];
        }
}

// ---------------------------------------------------------------------------
// Persistent ALIF scan v9: 1 block = 1 batch, 4 waves, 16 neurons/lane.
// Wave wv owns zb bits k ≡ wv (mod 4): 4 wave-uniform ballot masks; indices
// pulled by scalar ffs chain into 12 STATIC slots; all 24 row-loads issue
// before any accum (depth-12 — the r11 lesson: depth-2 can't hide ~400cy L2).
// No shfl prefix, no LDS spike list, ONE barrier/step (s_part parity-dbuf).
// ---------------------------------------------------------------------------
#define PULL(jq) {                                                            \
    if (!mm) { mm = mq1; kk = kq1; mq1 = 0; }                                 \
    if (!mm) { mm = mq2; kk = kq2; mq2 = 0; }                                 \
    if (!mm) { mm = mq3; kk = kq3; mq3 = 0; }                                 \
    if (mm) { jq = ((int)__ffsll(mm) - 1) * 16 + kk; mm &= mm - 1; }          \
    else jq = 1024; }

#define GLD(wa, wb, jq) {                                                     \
    const unsigned int* p_ = Wrow32 + ((size_t)(jq) << 9);                    \
    wa = *(const uint4*)p_;                                                   \
    wb = *(const uint4*)(p_ + 4); }

#define ACCP(c0_, c1_) {                                                      \
    rec[0]  += __uint_as_float(c0_.x << 16);                                  \
    rec[1]  += __uint_as_float(c0_.x & 0xFFFF0000u);                          \
    rec[2]  += __uint_as_float(c0_.y << 16);                                  \
    rec[3]  += __uint_as_float(c0_.y & 0xFFFF0000u);                          \
    rec[4]  += __uint_as_float(c0_.z << 16);                                  \
    rec[5]  += __uint_as_float(c0_.z & 0xFFFF0000u);                          \
    rec[6]  += __uint_as_float(c0_.w << 16);                                  \
    rec[7]  += __uint_as_float(c0_.w & 0xFFFF0000u);                          \
    rec[8]  += __uint_as_float(c1_.x << 16);                                  \
    rec[9]  += __uint_as_float(c1_.x & 0xFFFF0000u);                          \
    rec[10] += __uint_as_float(c1_.y << 16);                                  \
    rec[11] += __uint_as_float(c1_.y & 0xFFFF0000u);                          \
    rec[12] += __uint_as_float(c1_.z << 16);                                  \
    rec[13] += __uint_as_float(c1_.z & 0xFFFF0000u);                          \
    rec[14] += __uint_as_float(c1_.w << 16);                                  \
    rec[15] += __uint_as_float(c1_.w & 0xFFFF0000u); }

__global__ __launch_bounds__(256, 1)
void alif_scan(const float* __restrict__ CUR, const unsigned short* __restrict__ WhhT,
               const float* __restrict__ tau_mem, const float* __restrict__ tau_adp,
               float* __restrict__ zS, float* __restrict__ uS, float* __restrict__ aS,
               float* __restrict__ spkS, unsigned short* __restrict__ masks16,
               int t0, int tc) {
    const int tid  = threadIdx.x;
    const int wv   = tid >> 6;         // wave 0..3
    const int lane = tid & 63;
    const int b    = blockIdx.x;
    const int h0   = lane * 16;

    __shared__ __align__(16) f32x4 s_part[2][4][4][64];  // [parity][wave][q][lane]

    float u[16], a[16], alpha[16], rho[16];
#pragma unroll
    for (int q = 0; q < 4; ++q) {
        f32x4 uu = *(const f32x4*)(uS + (size_t)b * HID + h0 + q * 4);
        f32x4 aa = *(const f32x4*)(aS + (size_t)b * HID + h0 + q * 4);
        f32x4 tm = *(const f32x4*)(tau_mem + h0 + q * 4);
        f32x4 ta = *(const f32x4*)(tau_adp + h0 + q * 4);
#pragma unroll
        for (int k = 0; k < 4; ++k) {
            u[q * 4 + k] = uu[k];  a[q * 4 + k] = aa[k];
            alpha[q * 4 + k] = expf(-1.f / tm[k]);
            rho[q * 4 + k]   = expf(-1.f / ta[k]);
        }
    }
    unsigned int zb = 0;
#pragma unroll
    for (int q = 0; q < 4; ++q) {
        f32x4 zz = *(const f32x4*)(zS + (size_t)b * HID + h0 + q * 4);
#pragma unroll
        for (int k = 0; k < 4; ++k)
            if (zz[k] > 0.5f) zb |= (1u << (q * 4 + k));
    }

    const unsigned int* Wrow32 = (const unsigned int*)WhhT + (h0 >> 1);
    float xc[16];
#pragma unroll
    for (int q = 0; q < 4; ++q) {
        f32x4 v = *(const f32x4*)(CUR + (size_t)b * HID + h0 + q * 4);
        xc[q*4+0]=v[0]; xc[q*4+1]=v[1]; xc[q*4+2]=v[2]; xc[q*4+3]=v[3];
    }

    int wspk = 0;
    for (int tt = 0; tt < tc; ++tt) {
        // prefetch next step's input current (L2-resident chunk)
        float xn[16];
        {
            const int tn = (tt + 1 < tc) ? tt + 1 : tt;
            const float* p = CUR + ((size_t)tn * BATCH + b) * HID + h0;
#pragma unroll
            for (int q = 0; q < 4; ++q) {
                f32x4 v = *(const f32x4*)(p + q * 4);
                xn[q*4+0]=v[0]; xn[q*4+1]=v[1]; xn[q*4+2]=v[2]; xn[q*4+3]=v[3];
            }
        }

        // --- ballot masks for this wave's 4 bits (k = wv + 4i) ---
        u64 mm  = __ballot(((zb >> (wv + 0))  & 1u) != 0u);
        u64 mq1 = __ballot(((zb >> (wv + 4))  & 1u) != 0u);
        u64 mq2 = __ballot(((zb >> (wv + 8))  & 1u) != 0u);
        u64 mq3 = __ballot(((zb >> (wv + 12)) & 1u) != 0u);
        int kk = wv, kq1 = wv + 4, kq2 = wv + 8, kq3 = wv + 12;

        float rec[16];
#pragma unroll
        for (int k = 0; k < 16; ++k) rec[k] = 0.f;

        // --- extract 8 slots, issue 16 loads ---
        int j0, j1, j2, j3, j4, j5, j6, j7;
        PULL(j0); PULL(j1); PULL(j2); PULL(j3);
        PULL(j4); PULL(j5); PULL(j6); PULL(j7);
        uint4 w0a,w0b,w1a,w1b,w2a,w2b,w3a,w3b,w4a,w4b,w5a,w5b,w6a,w6b,w7a,w7b;
        GLD(w0a,w0b,j0); GLD(w1a,w1b,j1); GLD(w2a,w2b,j2); GLD(w3a,w3b,j3);
        GLD(w4a,w4b,j4); GLD(w5a,w5b,j5); GLD(w6a,w6b,j6); GLD(w7a,w7b,j7);

        // --- group 1 (slots 8-11) if spikes remain; issue before accum g0 ---
        const bool more1 = (mm | mq1 | mq2 | mq3) != 0ull;
        int j8, j9, j10, j11;
        uint4 w8a,w8b,w9a,w9b,w10a,w10b,w11a,w11b;
        if (more1) {
            PULL(j8); PULL(j9); PULL(j10); PULL(j11);
            GLD(w8a,w8b,j8); GLD(w9a,w9b,j9); GLD(w10a,w10b,j10); GLD(w11a,w11b,j11);
        }

        ACCP(w0a,w0b); ACCP(w1a,w1b); ACCP(w2a,w2b); ACCP(w3a,w3b);
        ACCP(w4a,w4b); ACCP(w5a,w5b); ACCP(w6a,w6b); ACCP(w7a,w7b);
        if (more1) {
            ACCP(w8a,w8b); ACCP(w9a,w9b); ACCP(w10a,w10b); ACCP(w11a,w11b);
            // rare tail (>12 spikes in this wave's bit-group): 4 at a time
            while ((mm | mq1 | mq2 | mq3) != 0ull) {
                PULL(j8); PULL(j9); PULL(j10); PULL(j11);
                GLD(w8a,w8b,j8); GLD(w9a,w9b,j9); GLD(w10a,w10b,j10); GLD(w11a,w11b,j11);
                ACCP(w8a,w8b); ACCP(w9a,w9b); ACCP(w10a,w10b); ACCP(w11a,w11b);
            }
        }

        // --- exchange partials (parity double-buffer, ONE barrier/step) ---
        const int pb = tt & 1;
        s_part[pb][wv][0][lane] = (f32x4){rec[0],  rec[1],  rec[2],  rec[3]};
        s_part[pb][wv][1][lane] = (f32x4){rec[4],  rec[5],  rec[6],  rec[7]};
        s_part[pb][wv][2][lane] = (f32x4){rec[8],  rec[9],  rec[10], rec[11]};
        s_part[pb][wv][3][lane] = (f32x4){rec[12], rec[13], rec[14], rec[15]};
        __syncthreads();
#pragma unroll
        for (int q = 0; q < 4; ++q) {
            f32x4 r0 = s_part[pb][0][q][lane];
            f32x4 r1 = s_part[pb][1][q][lane];
            f32x4 r2 = s_part[pb][2][q][lane];
            f32x4 r3 = s_part[pb][3][q][lane];
            f32x4 s = ((r0 + r1) + r2) + r3;   // fixed wave order
            rec[q*4+0] = s[0]; rec[q*4+1] = s[1];
            rec[q*4+2] = s[2]; rec[q*4+3] = s[3];
        }

        // --- neuron update: replicated identically in all 4 waves ---
        unsigned int znb = 0;
#pragma unroll
        for (int k = 0; k < 16; ++k) {
            const float z   = (zb >> k) & 1 ? 1.f : 0.f;
            const float omr = 1.f - rho[k];
            const float oma = 1.f - alpha[k];
            a[k] = rho[k] * a[k] + omr * z;
            const float th = 0.01f + 1.8f * a[k];
            u[k] = alpha[k] * u[k] + oma * (xc[k] + rec[k]) - z * th;
            if (u[k] - th > 0.f) znb |= (1u << k);
        }
        zb = znb;
        wspk += __popc(zb);
        if (wv == 0)
            masks16[((size_t)(t0 + tt) * BATCH + b) * 64 + lane] = (unsigned short)zb;

#pragma unroll
        for (int k = 0; k < 16; ++k) xc[k] = xn[k];
    }

    // write back state (wave 0 only — all waves identical)
    if (wv == 0) {
#pragma unroll
        for (int k = 0; k < 16; ++k) {
            zS[(size_t)b * HID + h0 + k] = (zb >> k) & 1 ? 1.f : 0.f;
            uS[(size_t)b * HID + h0 + k] = u[k];
            aS[(size_t)b * HID + h0 + k] = a[k];
        }
#pragma unroll
        for (int d = 32; d > 0; d >>= 1) wspk += __shfl_down(wspk, d, 64);
        if (lane == 0) atomicAdd(spkS, (float)wspk);
    }
}

// ---------------------------------------------------------------------------
// y[t*B+b][o] = sum over spiking j of WoT[j][o]  (one wave per (t,b) pair)
// ---------------------------------------------------------------------------
__global__ __launch_bounds__(256)
void readout_y(const u64* __restrict__ masks, const float* __restrict__ WoT,
               float* __restrict__ y, int npairs) {
    const int pr   = blockIdx.x * 4 + (threadIdx.x >> 6);
    const int lane = threadIdx.x & 63;
    if (pr >= npairs) return;
    const u64* mp = masks + (size_t)pr * 16;
    float acc = 0.f;
#pragma unroll 4
    for (int w = 0; w < 16; ++w) {
        u64 m = mp[w];
        while (m) {
            const int j = __ffsll((unsigned long long)m) - 1;
            m &= m - 1;
            if (lane < OUT_DIM) acc += WoT[(size_t)(w * 64 + j) * OUT_DIM + lane];
        }
    }
    if (lane < OUT_DIM) y[(size_t)pr * OUT_DIM + lane] = acc;
}

// ---------------------------------------------------------------------------
// outputs[t][b][o] = EWA over t of y; writes final ouT.
// ---------------------------------------------------------------------------
__global__ __launch_bounds__(256)
void ewa_out(const float* __restrict__ y, const float* __restrict__ tau_out,
             float* __restrict__ outputs, float* __restrict__ ouS) {
    const int idx = blockIdx.x * 256 + threadIdx.x;
    if (idx >= BATCH * OUT_DIM) return;
    const int o = idx % OUT_DIM;
    const float ao = expf(-1.f / tau_out[o]);
    float ou = ouS[idx];
    for (int t = 0; t < T_STEPS; ++t) {
        const float v = y[(size_t)t * BATCH * OUT_DIM + idx];
        ou = ao * ou + (1.f - ao) * v;
        outputs[(size_t)t * BATCH * OUT_DIM + idx] = ou;
    }
    ouS[idx] = ou;
}

// ---------------------------------------------------------------------------
extern "C" void kernel_launch(void* const* d_in, const int* in_sizes, int n_in,
                              void* d_out, int out_size, void* d_ws, size_t ws_size,
                              hipStream_t stream) {
    (void)in_sizes; (void)n_in; (void)out_size;
    const float* x       = (const float*)d_in[0];
    const float* W_h     = (const float*)d_in[1];
    const float* tau_mem = (const float*)d_in[2];
    const float* tau_adp = (const float*)d_in[3];
    const float* W_o     = (const float*)d_in[4];
    const float* tau_out = (const float*)d_in[5];

    float* out     = (float*)d_out;
    float* outputs = out;                                      // [250][256][20]
    float* zS  = out + (size_t)T_STEPS * BATCH * OUT_DIM;      // [256][1024]
    float* uS  = zS + (size_t)BATCH * HID;
    float* aS  = uS + (size_t)BATCH * HID;
    float* ouS = aS + (size_t)BATCH * HID;                     // [256][20]
    float* spk = ouS + (size_t)BATCH * OUT_DIM;                // scalar

    // ws layout (bytes)
    char* w = (char*)d_ws;
    unsigned short* WhhT = (unsigned short*)w; w += (size_t)(HID + 1) * HID * 2;  // 2 MB + zero row
    unsigned short* Wp   = (unsigned short*)w; w += (size_t)HID * KP * 2;         // 1.4 MB
    float*          WoT  = (float*)w;          w += (size_t)HID * OUT_DIM * 4;    // 80 KB
    unsigned short* masks16 = (unsigned short*)w; w += (size_t)T_STEPS * BATCH * 128; // 8 MB
    float*          yBuf = (float*)w;          w += (size_t)T_STEPS * BATCH * OUT_DIM * 4; // 5 MB
    char*           dynb = w;

    const size_t fixed = (size_t)(dynb - (char*)d_ws);
    const size_t per_step = (size_t)BATCH * KP * 2 + (size_t)BATCH * HID * 4;
    const size_t avail = ws_size > fixed ? ws_size - fixed : 0;
    int CT = (int)(avail / per_step);
    if (CT > CHUNK_T) CT = CHUNK_T;
    if (CT < 1) CT = 1;

    hipMemsetAsync(zS, 0,
                   ((size_t)3 * BATCH * HID + BATCH * OUT_DIM + 1) * sizeof(float),
                   stream);
    hipMemsetAsync(WhhT + (size_t)HID * HID, 0, HID * sizeof(unsigned short), stream);
    trans_whh_bf16<<<dim3(32, 32), dim3(32, 8), 0, stream>>>(W_h, WhhT);
    pack_w_bf16<<<512, 256, 0, stream>>>(W_h, Wp);
    trans_wo<<<4, 256, 0, stream>>>(W_o, WoT);

    for (int t0 = 0; t0 < T_STEPS; t0 += CT) {
        const int tc = (T_STEPS - t0 < CT) ? (T_STEPS - t0) : CT;
        const int rows = tc * BATCH;
        unsigned short* Xp = (unsigned short*)dynb;
        float* CUR = (float*)(dynb + (size_t)rows * KP * 2);
        int pblocks = (rows * KP4 + 255) / 256;
        if (pblocks > 2048) pblocks = 2048;
        pack_x_bf16<<<pblocks, 256, 0, stream>>>(x + (size_t)t0 * BATCH * IN_DIM, Xp, rows);
        mfma_gemm<<<dim3(rows / 128, HID / 128), 256, 0, stream>>>(Xp, Wp, CUR);
        alif_scan<<<BATCH, 256, 0, stream>>>(CUR, WhhT, tau_mem, tau_adp,
                                             zS, uS, aS, spk, masks16, t0, tc);
    }

    const int npairs = T_STEPS * BATCH;
    readout_y<<<(npairs + 3) / 4, 256, 0, stream>>>((const u64*)masks16, WoT, yBuf, npairs);
    ewa_out<<<(BATCH * OUT_DIM + 255) / 256, 256, 0, stream>>>(yBuf, tau_out, outputs, ouS);
}